// Round 1
// baseline (276.151 us; speedup 1.0000x reference)
//
#include <hip/hip_runtime.h>
#include <hip/hip_bf16.h>
#include <cstdint>

#define GAMMA 0.001f

typedef __attribute__((ext_vector_type(8))) short bh8;   // 8 bf16 = 4 VGPRs
typedef __attribute__((ext_vector_type(4))) float f32x4;

// ---------------------------------------------------------------------------
// Kernel 1: support prep — f32 -> bf16 (rows padded 784->800 with zeros),
// s2 = sum(row^2), beta[m,c] = exp(-gamma*s2)*alpha[m,c]
// ---------------------------------------------------------------------------
__global__ __launch_bounds__(256) void prep_support_kernel(
    const float* __restrict__ support, const float* __restrict__ alpha,
    ushort* __restrict__ sup_bf, float* __restrict__ beta) {
  int m = blockIdx.x;
  int tid = threadIdx.x;
  __shared__ float red[256];
  float ss = 0.f;
  if (tid < 196) {
    float4 v = ((const float4*)(support + (size_t)m * 784))[tid];
    ss = v.x * v.x + v.y * v.y + v.z * v.z + v.w * v.w;
    ushort4 p;
    __hip_bfloat16 h;
    h = __float2bfloat16(v.x); p.x = *(ushort*)&h;
    h = __float2bfloat16(v.y); p.y = *(ushort*)&h;
    h = __float2bfloat16(v.z); p.z = *(ushort*)&h;
    h = __float2bfloat16(v.w); p.w = *(ushort*)&h;
    *(ushort4*)(sup_bf + (size_t)m * 800 + tid * 4) = p;
  } else if (tid < 200) {  // pad 784..799
    ushort4 z = {0, 0, 0, 0};
    *(ushort4*)(sup_bf + (size_t)m * 800 + tid * 4) = z;
  }
  red[tid] = ss;
  __syncthreads();
  for (int s = 128; s > 0; s >>= 1) {
    if (tid < s) red[tid] += red[tid + s];
    __syncthreads();
  }
  if (tid == 0) {
    float es = __expf(-GAMMA * red[0]);
    float4 a = ((const float4*)alpha)[m];
    float4 b;
    b.x = es * a.x; b.y = es * a.y; b.z = es * a.z; b.w = es * a.w;
    ((float4*)beta)[m] = b;
  }
}

// ---------------------------------------------------------------------------
// Kernel 2: fused conv1+pool+conv2+pool per image. One block per image.
// Zero-padded LDS planes -> no boundary branches in the conv loops.
// Emits bf16 feats (padded to 800) + ef[n] = exp(-gamma*|f|^2). Zeros out.
// ---------------------------------------------------------------------------
__global__ __launch_bounds__(256) void conv_feats_kernel(
    const float* __restrict__ x, const float* __restrict__ w1,
    const float* __restrict__ b1, const float* __restrict__ w2,
    const float* __restrict__ b2, ushort* __restrict__ feats_bf,
    float* __restrict__ ef, float* __restrict__ out) {
  int n = blockIdx.x, tid = threadIdx.x;
  __shared__ float xp[30 * 30];       // padded 28x28
  __shared__ float a1p[8 * 16 * 16];  // padded 8x14x14
  __shared__ float w1s[72], b1s[8], w2s[1152], b2s[16];
  __shared__ float red[256];

  for (int t = tid; t < 900; t += 256) xp[t] = 0.f;
  for (int t = tid; t < 2048; t += 256) a1p[t] = 0.f;
  if (tid < 72) w1s[tid] = w1[tid];
  if (tid < 8) b1s[tid] = b1[tid];
  for (int t = tid; t < 1152; t += 256) w2s[t] = w2[t];
  if (tid < 16) b2s[tid] = b2[tid];
  if (tid < 4) out[n * 4 + tid] = 0.f;  // zero output (poisoned 0xAA)
  __syncthreads();

  if (tid < 196) {  // load image into padded interior (float4 never straddles rows: 28%4==0)
    float4 v = ((const float4*)(x + (size_t)n * 784))[tid];
    int e = tid * 4, r = e / 28, c = e % 28;
    float* p = &xp[(r + 1) * 30 + (c + 1)];
    p[0] = v.x; p[1] = v.y; p[2] = v.z; p[3] = v.w;
  }
  __syncthreads();

  // stage 1: conv1(3x3,SAME) + bias + relu + maxpool2 -> a1p[8][16][16] interior
  for (int idx = tid; idx < 1568; idx += 256) {
    int c = idx / 196, rem = idx % 196;
    int ph = rem / 14, pw = rem % 14;
    const float* w = &w1s[c * 9];
    float t[4][4];
#pragma unroll
    for (int a = 0; a < 4; a++)
#pragma unroll
      for (int b = 0; b < 4; b++) t[a][b] = xp[(2 * ph + a) * 30 + (2 * pw + b)];
    float s00 = 0, s01 = 0, s10 = 0, s11 = 0;
#pragma unroll
    for (int dy = 0; dy < 3; dy++)
#pragma unroll
      for (int dx = 0; dx < 3; dx++) {
        float wv = w[dy * 3 + dx];
        s00 += t[dy][dx] * wv;     s01 += t[dy][dx + 1] * wv;
        s10 += t[dy + 1][dx] * wv; s11 += t[dy + 1][dx + 1] * wv;
      }
    float mx = fmaxf(fmaxf(s00, s01), fmaxf(s10, s11));
    a1p[c * 256 + (ph + 1) * 16 + (pw + 1)] = fmaxf(mx + b1s[c], 0.f);
  }
  __syncthreads();

  // stage 2: conv2(8ch,3x3,SAME) + bias + relu + maxpool2 -> feats
  float fsq = 0.f;
  for (int idx = tid; idx < 784; idx += 256) {
    int o = idx / 49, rem = idx % 49;
    int y7 = rem / 7, x7 = rem % 7;
    float s00 = 0, s01 = 0, s10 = 0, s11 = 0;
#pragma unroll
    for (int ic = 0; ic < 8; ic++) {
      float t[4][4];
      const float* ap = &a1p[ic * 256 + (2 * y7) * 16 + 2 * x7];
#pragma unroll
      for (int a = 0; a < 4; a++)
#pragma unroll
        for (int b = 0; b < 4; b++) t[a][b] = ap[a * 16 + b];
      const float* w = &w2s[(o * 8 + ic) * 9];
#pragma unroll
      for (int dy = 0; dy < 3; dy++)
#pragma unroll
        for (int dx = 0; dx < 3; dx++) {
          float wv = w[dy * 3 + dx];
          s00 += t[dy][dx] * wv;     s01 += t[dy][dx + 1] * wv;
          s10 += t[dy + 1][dx] * wv; s11 += t[dy + 1][dx + 1] * wv;
        }
    }
    float mx = fmaxf(fmaxf(s00, s01), fmaxf(s10, s11));
    float val = fmaxf(mx + b2s[o], 0.f);
    __hip_bfloat16 h = __float2bfloat16(val);
    feats_bf[(size_t)n * 800 + idx] = *(ushort*)&h;
    fsq += val * val;
  }
  if (tid < 16) feats_bf[(size_t)n * 800 + 784 + tid] = 0;  // pad
  red[tid] = fsq;
  __syncthreads();
  for (int s = 128; s > 0; s >>= 1) {
    if (tid < s) red[tid] += red[tid + s];
    __syncthreads();
  }
  if (tid == 0) ef[n] = __expf(-GAMMA * red[0]);
}

// ---------------------------------------------------------------------------
// Kernel 3: fused RBF GEMM. 128x128 bf16 MFMA tiles over K=800,
// epilogue: K=exp(2g*G) folded into out[n,c] += K*beta[m,c]; scaled by ef[n].
// Grid: 32 n-blocks x 16 m-chunks (512 rows each) = 512 blocks; chunk=bx&15
// keeps each support chunk L2-resident on one XCD (bx%8 swizzle heuristic).
// ---------------------------------------------------------------------------
__global__ __launch_bounds__(256, 2) void rbf_gemm_kernel(
    const ushort* __restrict__ feats, const ushort* __restrict__ sup,
    const float* __restrict__ beta, const float* __restrict__ ef,
    float* __restrict__ out) {
  __shared__ ushort As[128 * 32];
  __shared__ ushort Bs[128 * 32];
  int tid = threadIdx.x;
  int wave = tid >> 6, lane = tid & 63;
  int bx = blockIdx.x;
  int chunk = bx & 15, nb = bx >> 4;
  int n0 = nb * 128;
  int mbase = chunk * 512;
  int wn = wave >> 1, wm = wave & 1;
  int col = lane & 15, quad = lane >> 4;
  int lr = lane >> 2, lc = (lane & 3) * 8;

  f32x4 oa[4][4];  // [i-frag][row-reg] over 4 classes
#pragma unroll
  for (int i = 0; i < 4; i++)
#pragma unroll
    for (int r = 0; r < 4; r++) oa[i][r] = (f32x4){0, 0, 0, 0};

  for (int mt = 0; mt < 4; ++mt) {
    int m0 = mbase + mt * 128;
    f32x4 acc[4][4];
#pragma unroll
    for (int i = 0; i < 4; i++)
#pragma unroll
      for (int j = 0; j < 4; j++) acc[i][j] = (f32x4){0, 0, 0, 0};

    for (int kk = 0; kk < 25; ++kk) {
      int k0 = kk * 32;
#pragma unroll
      for (int i = 0; i < 2; i++) {
        int row = wave * 32 + i * 16 + lr;
        const ushort* ga = feats + (size_t)(n0 + row) * 800 + k0 + lc;
        ushort* la = (ushort*)As + row * 32 + lc;
        __builtin_amdgcn_global_load_lds(
            (const __attribute__((address_space(1))) void*)ga,
            (__attribute__((address_space(3))) void*)la, 16, 0, 0);
        const ushort* gb = sup + (size_t)(m0 + row) * 800 + k0 + lc;
        ushort* lb = (ushort*)Bs + row * 32 + lc;
        __builtin_amdgcn_global_load_lds(
            (const __attribute__((address_space(1))) void*)gb,
            (__attribute__((address_space(3))) void*)lb, 16, 0, 0);
      }
      __syncthreads();
      bh8 af[4], bf[4];
#pragma unroll
      for (int i = 0; i < 4; i++)
        af[i] = *(const bh8*)(As + (wn * 64 + i * 16 + col) * 32 + quad * 8);
#pragma unroll
      for (int j = 0; j < 4; j++)
        bf[j] = *(const bh8*)(Bs + (wm * 64 + j * 16 + col) * 32 + quad * 8);
#pragma unroll
      for (int i = 0; i < 4; i++)
#pragma unroll
        for (int j = 0; j < 4; j++)
          acc[i][j] = __builtin_amdgcn_mfma_f32_16x16x32_bf16(af[i], bf[j],
                                                              acc[i][j], 0, 0, 0);
      __syncthreads();
    }

    // epilogue: C/D layout col=lane&15 (m), row=quad*4+r (n)
#pragma unroll
    for (int j = 0; j < 4; j++) {
      int m = m0 + wm * 64 + j * 16 + col;
      float4 bt = ((const float4*)beta)[m];
#pragma unroll
      for (int i = 0; i < 4; i++)
#pragma unroll
        for (int r = 0; r < 4; r++) {
          float Kv = __expf(2.f * GAMMA * acc[i][j][r]);
          oa[i][r].x += Kv * bt.x; oa[i][r].y += Kv * bt.y;
          oa[i][r].z += Kv * bt.z; oa[i][r].w += Kv * bt.w;
        }
    }
  }

  // reduce over the 16 lanes sharing the same n (col dimension)
#pragma unroll
  for (int i = 0; i < 4; i++)
#pragma unroll
    for (int r = 0; r < 4; r++) {
      f32x4 v = oa[i][r];
#pragma unroll
      for (int s = 1; s < 16; s <<= 1) {
        v.x += __shfl_xor(v.x, s, 16);
        v.y += __shfl_xor(v.y, s, 16);
        v.z += __shfl_xor(v.z, s, 16);
        v.w += __shfl_xor(v.w, s, 16);
      }
      oa[i][r] = v;
    }
  if (col < 4) {
#pragma unroll
    for (int i = 0; i < 4; i++)
#pragma unroll
      for (int r = 0; r < 4; r++) {
        int n = n0 + wn * 64 + i * 16 + quad * 4 + r;
        f32x4 v = oa[i][r];
        float val = (col == 0) ? v.x : (col == 1) ? v.y : (col == 2) ? v.z : v.w;
        atomicAdd(&out[n * 4 + col], ef[n] * val);
      }
  }
}

// ---------------------------------------------------------------------------
extern "C" void kernel_launch(void* const* d_in, const int* in_sizes, int n_in,
                              void* d_out, int out_size, void* d_ws,
                              size_t ws_size, hipStream_t stream) {
  const float* x = (const float*)d_in[0];
  const float* w1 = (const float*)d_in[1];
  const float* b1 = (const float*)d_in[2];
  const float* w2 = (const float*)d_in[3];
  const float* b2 = (const float*)d_in[4];
  const float* support = (const float*)d_in[5];
  const float* alpha = (const float*)d_in[6];
  float* out = (float*)d_out;

  char* ws = (char*)d_ws;
  ushort* sup_bf = (ushort*)ws;                  // 8192*800*2 = 13,107,200 B
  ushort* feats_bf = (ushort*)(ws + 13107200);   // 4096*800*2 =  6,553,600 B
  float* beta = (float*)(ws + 19660800);         // 8192*4*4   =    131,072 B
  float* ef = (float*)(ws + 19791872);           // 4096*4     =     16,384 B

  prep_support_kernel<<<8192, 256, 0, stream>>>(support, alpha, sup_bf, beta);
  conv_feats_kernel<<<4096, 256, 0, stream>>>(x, w1, b1, w2, b2, feats_bf, ef, out);
  rbf_gemm_kernel<<<512, 256, 0, stream>>>(feats_bf, sup_bf, beta, ef, out);
}